// Round 9
// baseline (176.827 us; speedup 1.0000x reference)
//
#include <hip/hip_runtime.h>
#include <hip/hip_bf16.h>
#include <hip/hip_cooperative_groups.h>

namespace cg = cooperative_groups;

// Problem constants (from reference)
#define NN    4096
#define DD    256
#define HH    4
#define DHH   64
#define EDGES 131072
#define CAP   128           // per-row neighbor capacity; deg ~ Poisson(32), P(>128) < 1e-40
#define LRELU_ALPHA 0.2f

typedef __hip_bfloat16 bf16;
typedef __attribute__((ext_vector_type(8))) short short8v;   // 8 bf16 = 4 VGPR
typedef __attribute__((ext_vector_type(4))) float f32x4;     // MFMA acc

// Round-14: SINGLE COOPERATIVE KERNEL. R7/R8 showed profiled-vs-timed
// disagreement and nothing of ours cracks the 41us fill cutoff -> blind.
// Fusing memset+edges+hproj+attn into one dispatch (grid 256 x 1024 = exactly
// 1 block/CU, two grid.sync()) deletes 2 launch gaps + 1 memset dispatch AND
// makes our entire GPU time visible as one top-5 row with full counters.
// Phase 1 is R8's hproj verbatim (same LDS split-bf16 fragment records, same
// MFMA order -> hb/esrc/edst bit-identical, absmax 0.03125 exactly).
// Phase 2 is the unchanged attn math, wave = row, 16 rows/block.
// LDS: phase-1 struct 82KB unioned with phase-2 40KB (reuse across grid.sync).
//
// ws layout, 4.2 MB total:
//   hb    [N][H][DH]   bf16  @ 0         (2 MB)
//   esrc  [N][H]       f32   @ 2097152   (64 KB)
//   edst  [N][H]       f32   @ 2162688   (64 KB)
//   bmg   [N][N/32]    u32   @ 2228224   (2 MB)   <- zeroed in phase 0
//
// Harness floor per iteration: 256 MiB 0xAA ws re-poison fill ~42us (flushes
// L2+L3 -> our kernel starts cold) + input-restore dispatches. Untouchable.

__device__ __forceinline__ float bf_lo(unsigned int u) { return __uint_as_float(u << 16); }
__device__ __forceinline__ float bf_hi(unsigned int u) { return __uint_as_float(u & 0xffff0000u); }

__device__ __forceinline__ unsigned short f2bf_rne(float f) {
    unsigned int u = __float_as_uint(f);
    return (unsigned short)((u + 0x7fffu + ((u >> 16) & 1u)) >> 16);   // RNE; no NaN here
}
__device__ __forceinline__ float bf2f(unsigned short s) {
    return __uint_as_float(((unsigned int)s) << 16);
}

struct Phase1LDS {
    unsigned short wlhi[2048 * 10];   // record = 8 shorts + 2 pad (20 B)
    unsigned short wllo[2048 * 10];
    float pvs[16][16];
    float pvd[16][16];
};
struct Phase2LDS {
    int   nbr[16][CAP];
    float wts[16][CAP][HH];
};
union FusedLDS { Phase1LDS p1; Phase2LDS p2; };

// ---------------------------------------------------------------------------
// grid = 256 blocks x 1024 threads (1 block/CU, co-resident; LDS 82KB).
// Phase 0: zero bmg.  sync.
// Phase 1: edges (512/block, fire-and-forget atomicOr) + MFMA hproj:
//   block = (64-row M-tile, head = blk&3), 16 waves = (m = wv>>2, q = wv&3),
//   W[h] staged once into LDS as split-bf16 fragment records (20B stride,
//   gcd(5,32)=1 -> conflict-free dword reads), 8 K-steps x 3 split MFMAs.
//   sync.
// Phase 2: attn, wave = row (16 rows/block): bitmask -> shfl-prefix compact,
//   float4 logits (all heads/lane), expf in LDS, 4x-unrolled uint2 PV gather.
// ---------------------------------------------------------------------------
__global__ __launch_bounds__(1024, 4) void fused_kernel(
    const float* __restrict__ x, const float* __restrict__ ev,
    const float* __restrict__ W, const float* __restrict__ a_src,
    const float* __restrict__ a_dst, const int* __restrict__ ei,
    bf16* __restrict__ hb, float* __restrict__ esrc, float* __restrict__ edst,
    unsigned int* __restrict__ bmg, float* __restrict__ out)
{
    __shared__ FusedLDS sh;
    cg::grid_group grid = cg::this_grid();

    const int t   = threadIdx.x;
    const int blk = blockIdx.x;

    // ---------------- phase 0: zero bmg (2 words/thread) ----------------
    ((uint2*)bmg)[blk * 1024 + t] = make_uint2(0u, 0u);
    grid.sync();

    // ---------------- phase 1: edges + MFMA hproj ----------------
    {
        const int h  = blk & 3;         // head
        const int i0 = (blk >> 2) * 64; // M-tile base row

        // edge slice: 512 edges/block, 1 per thread for t<512
        if (t < 512) {
            const int   e  = blk * 512 + t;
            const float vv = ev[e];
            const int   er = ei[e];            // edge_index[0][e]
            const int   ec = ei[EDGES + e];    // edge_index[1][e]
            if (vv > 0.f)
                atomicOr(&bmg[er * (NN / 32) + (ec >> 5)], 1u << (ec & 31));
        }

        // stage W[h] (64 KB fp32) -> split-bf16 fragment records in LDS
        {
            const float4* Ws = (const float4*)(W + (size_t)h * (DD * DHH));
            #pragma unroll
            for (int j = 0; j < 4; ++j) {
                const int fi = t + j * 1024;          // float4 index, coalesced
                const float4 f = Ws[fi];
                const float v[4] = {f.x, f.y, f.z, f.w};
                #pragma unroll
                for (int c = 0; c < 4; ++c) {
                    const int lin = fi * 4 + c;       // = d*64 + dh
                    const int d = lin >> 6, dh = lin & 63;
                    const int rec = (((dh >> 4) * 8 + (d >> 5)) << 6)
                                  + ((d >> 3) & 3) * 16 + (dh & 15);
                    const int off = rec * 10 + (d & 7);
                    const unsigned short hi = f2bf_rne(v[c]);
                    sh.p1.wlhi[off] = hi;
                    sh.p1.wllo[off] = f2bf_rne(v[c] - bf2f(hi));
                }
            }
        }
        __syncthreads();

        const int wv   = t >> 6;        // 0..15
        const int m    = wv >> 2;       // M-subtile (16 rows)
        const int q    = wv & 3;        // N-subtile (16 cols within head)
        const int lane = t & 63;
        const int mrow = lane & 15;     // A row / C col index
        const int kgrp = lane >> 4;     // k-group / C row group

        const float* xp = x + (size_t)(i0 + m * 16 + mrow) * DD + 8 * kgrp;
        const unsigned int* hi32 = (const unsigned int*)sh.p1.wlhi;
        const unsigned int* lo32 = (const unsigned int*)sh.p1.wllo;

        f32x4 acc = (f32x4){0.f, 0.f, 0.f, 0.f};

        #pragma unroll
        for (int ks = 0; ks < 8; ++ks) {
            // A fragment: x split hi/lo on the fly
            const float4 u0 = *(const float4*)(xp + ks * 32);
            const float4 u1 = *(const float4*)(xp + ks * 32 + 4);
            const float v[8] = {u0.x, u0.y, u0.z, u0.w, u1.x, u1.y, u1.z, u1.w};
            short8v ah, al;
            #pragma unroll
            for (int e = 0; e < 8; ++e) {
                const unsigned short hi = f2bf_rne(v[e]);
                ah[e] = (short)hi;
                al[e] = (short)f2bf_rne(v[e] - bf2f(hi));
            }
            // B fragment: 4+4 conflict-free LDS dwords, bit-alias into short8v
            const int rb = ((q * 8 + ks) * 64 + lane) * 5;
            union { unsigned int u[4]; short8v s; } bh, bl;
            #pragma unroll
            for (int k = 0; k < 4; ++k) {
                bh.u[k] = hi32[rb + k];
                bl.u[k] = lo32[rb + k];
            }
            acc = __builtin_amdgcn_mfma_f32_16x16x32_bf16(ah, bh.s, acc, 0, 0, 0);
            acc = __builtin_amdgcn_mfma_f32_16x16x32_bf16(ah, bl.s, acc, 0, 0, 0);
            acc = __builtin_amdgcn_mfma_f32_16x16x32_bf16(al, bh.s, acc, 0, 0, 0);
        }

        // hb store: C/D mapping col=mrow (within this q-tile), row=4*kgrp+reg
        {
            const int col = h * 64 + q * 16 + mrow;
            #pragma unroll
            for (int reg = 0; reg < 4; ++reg) {
                const int row = i0 + m * 16 + 4 * kgrp + reg;
                hb[(size_t)row * (HH * DHH) + col] = __float2bfloat16(acc[reg]);
            }
        }

        // esrc/edst partials: dot over this wave's 16 dh, 16-lane shfl tree
        {
            const float as = a_src[h * DHH + q * 16 + mrow];
            const float ad = a_dst[h * DHH + q * 16 + mrow];
            float vs[4], vd[4];
            #pragma unroll
            for (int reg = 0; reg < 4; ++reg) {
                vs[reg] = acc[reg] * as;
                vd[reg] = acc[reg] * ad;
            }
            #pragma unroll
            for (int reg = 0; reg < 4; ++reg) {
                #pragma unroll
                for (int off = 1; off < 16; off <<= 1) {
                    vs[reg] += __shfl_xor(vs[reg], off, 64);
                    vd[reg] += __shfl_xor(vd[reg], off, 64);
                }
            }
            if (mrow == 0) {
                #pragma unroll
                for (int reg = 0; reg < 4; ++reg) {
                    sh.p1.pvs[wv][4 * kgrp + reg] = vs[reg];
                    sh.p1.pvd[wv][4 * kgrp + reg] = vd[reg];
                }
            }
        }
        __syncthreads();

        // final reduce: q-ascending deterministic sum (bit-identical to R8)
        if (q == 0 && lane < 16) {
            float s = 0.f, d = 0.f;
            #pragma unroll
            for (int qq = 0; qq < 4; ++qq) {
                s += sh.p1.pvs[m * 4 + qq][lane];
                d += sh.p1.pvd[m * 4 + qq][lane];
            }
            const int row = i0 + m * 16 + lane;
            esrc[row * HH + h] = s;
            edst[row * HH + h] = d;
        }
    }
    grid.sync();

    // ---------------- phase 2: attn, wave = row ----------------
    {
        const int w = t >> 6, lane = t & 63;
        const int i = blk * 16 + w;

        // bitmask -> compact neighbor list (wave-parallel, no atomics)
        const uint2 wp = *(const uint2*)(bmg + (size_t)i * (NN / 32) + 2 * lane);
        const int c = __popc(wp.x) + __popc(wp.y);
        int inc = c;
        #pragma unroll
        for (int off = 1; off < 64; off <<= 1) {
            const int nn = __shfl_up(inc, off, 64);
            if (lane >= off) inc += nn;
        }
        int p = inc - c;
        const int deg = min(__shfl(inc, 63, 64), CAP);
        unsigned int bw = wp.x;
        while (bw) { const int b = __ffs(bw) - 1; bw &= bw - 1; if (p < CAP) sh.p2.nbr[w][p] = (lane << 6) + b; ++p; }
        bw = wp.y;
        while (bw) { const int b = __ffs(bw) - 1; bw &= bw - 1; if (p < CAP) sh.p2.nbr[w][p] = (lane << 6) + 32 + b; ++p; }
        __syncthreads();

        const int head = lane >> 4;          // lane covers dims [4*lane, 4*lane+3]
        float4 acc = make_float4(0.f, 0.f, 0.f, 0.f);
        float4 sm  = make_float4(0.f, 0.f, 0.f, 0.f);

        if (deg > 0) {
            const float4 es4 = *(const float4*)(esrc + (size_t)i * HH);
            float4 mx = make_float4(-INFINITY, -INFINITY, -INFINITY, -INFINITY);
            // pass 1: logits (all 4 heads per lane), track max
            for (int k = lane; k < deg; k += 64) {
                const float4 ed = *(const float4*)(edst + (size_t)sh.p2.nbr[w][k] * HH);
                float4 e4;
                e4.x = es4.x + ed.x; e4.x = e4.x > 0.f ? e4.x : LRELU_ALPHA * e4.x;
                e4.y = es4.y + ed.y; e4.y = e4.y > 0.f ? e4.y : LRELU_ALPHA * e4.y;
                e4.z = es4.z + ed.z; e4.z = e4.z > 0.f ? e4.z : LRELU_ALPHA * e4.z;
                e4.w = es4.w + ed.w; e4.w = e4.w > 0.f ? e4.w : LRELU_ALPHA * e4.w;
                *(float4*)&sh.p2.wts[w][k][0] = e4;
                mx.x = fmaxf(mx.x, e4.x); mx.y = fmaxf(mx.y, e4.y);
                mx.z = fmaxf(mx.z, e4.z); mx.w = fmaxf(mx.w, e4.w);
            }
            #pragma unroll
            for (int off = 32; off; off >>= 1) {
                mx.x = fmaxf(mx.x, __shfl_xor(mx.x, off, 64));
                mx.y = fmaxf(mx.y, __shfl_xor(mx.y, off, 64));
                mx.z = fmaxf(mx.z, __shfl_xor(mx.z, off, 64));
                mx.w = fmaxf(mx.w, __shfl_xor(mx.w, off, 64));
            }
            // pass 2: exponentiate in place, track sum
            for (int k = lane; k < deg; k += 64) {
                float4 e4 = *(const float4*)&sh.p2.wts[w][k][0];
                e4.x = expf(e4.x - mx.x); e4.y = expf(e4.y - mx.y);
                e4.z = expf(e4.z - mx.z); e4.w = expf(e4.w - mx.w);
                *(float4*)&sh.p2.wts[w][k][0] = e4;
                sm.x += e4.x; sm.y += e4.y; sm.z += e4.z; sm.w += e4.w;
            }
            #pragma unroll
            for (int off = 32; off; off >>= 1) {
                sm.x += __shfl_xor(sm.x, off, 64);
                sm.y += __shfl_xor(sm.y, off, 64);
                sm.z += __shfl_xor(sm.z, off, 64);
                sm.w += __shfl_xor(sm.w, off, 64);
            }
        }
        __syncthreads();   // uniform barrier count across the 16 waves

        float inv;
        if (deg == 0) {
            // uniform attention over all N columns: out = mean of h
            const uint2* hp = (const uint2*)hb + lane;   // row j = 64 uint2's
            for (int j = 0; j < NN; ++j) {
                const uint2 u = hp[(size_t)j * 64];
                acc.x += bf_lo(u.x); acc.y += bf_hi(u.x);
                acc.z += bf_lo(u.y); acc.w += bf_hi(u.y);
            }
            inv = 1.f / NN;
        } else {
            // pass 3: acc_d = sum_k w[head][k] * h[j_k][d]; 4 gathers in flight
            const uint2* hp = (const uint2*)hb;
            int k = 0;
            for (; k + 3 < deg; k += 4) {
                const int j0 = sh.p2.nbr[w][k],     j1 = sh.p2.nbr[w][k + 1];
                const int j2 = sh.p2.nbr[w][k + 2], j3 = sh.p2.nbr[w][k + 3];
                const uint2 u0 = hp[(size_t)j0 * 64 + lane];
                const uint2 u1 = hp[(size_t)j1 * 64 + lane];
                const uint2 u2 = hp[(size_t)j2 * 64 + lane];
                const uint2 u3 = hp[(size_t)j3 * 64 + lane];
                const float w0 = sh.p2.wts[w][k][head],     w1 = sh.p2.wts[w][k + 1][head];
                const float w2 = sh.p2.wts[w][k + 2][head], w3 = sh.p2.wts[w][k + 3][head];
                acc.x = fmaf(w0, bf_lo(u0.x), acc.x); acc.y = fmaf(w0, bf_hi(u0.x), acc.y);
                acc.z = fmaf(w0, bf_lo(u0.y), acc.z); acc.w = fmaf(w0, bf_hi(u0.y), acc.w);
                acc.x = fmaf(w1, bf_lo(u1.x), acc.x); acc.y = fmaf(w1, bf_hi(u1.x), acc.y);
                acc.z = fmaf(w1, bf_lo(u1.y), acc.z); acc.w = fmaf(w1, bf_hi(u1.y), acc.w);
                acc.x = fmaf(w2, bf_lo(u2.x), acc.x); acc.y = fmaf(w2, bf_hi(u2.x), acc.y);
                acc.z = fmaf(w2, bf_lo(u2.y), acc.z); acc.w = fmaf(w2, bf_hi(u2.y), acc.w);
                acc.x = fmaf(w3, bf_lo(u3.x), acc.x); acc.y = fmaf(w3, bf_hi(u3.x), acc.y);
                acc.z = fmaf(w3, bf_lo(u3.y), acc.z); acc.w = fmaf(w3, bf_hi(u3.y), acc.w);
            }
            for (; k < deg; ++k) {
                const uint2 u = hp[(size_t)sh.p2.nbr[w][k] * 64 + lane];
                const float wk = sh.p2.wts[w][k][head];
                acc.x = fmaf(wk, bf_lo(u.x), acc.x); acc.y = fmaf(wk, bf_hi(u.x), acc.y);
                acc.z = fmaf(wk, bf_lo(u.y), acc.z); acc.w = fmaf(wk, bf_hi(u.y), acc.w);
            }
            const float s = head == 0 ? sm.x : head == 1 ? sm.y : head == 2 ? sm.z : sm.w;
            inv = 1.f / s;
        }

        float4 o;
        o.x = acc.x * inv; o.y = acc.y * inv; o.z = acc.z * inv; o.w = acc.w * inv;
        *(float4*)(out + (size_t)i * (HH * DHH) + 4 * lane) = o;   // fp32 output
    }
}

// ---------------------------------------------------------------------------
extern "C" void kernel_launch(void* const* d_in, const int* in_sizes, int n_in,
                              void* d_out, int out_size, void* d_ws, size_t ws_size,
                              hipStream_t stream)
{
    const float* x     = (const float*)d_in[0];
    const float* ev    = (const float*)d_in[1];
    // d_in[2..5] = W1,b1,W2,b2 (edge MLP) -- provably irrelevant to the output
    const float* W     = (const float*)d_in[6];
    const float* a_src = (const float*)d_in[7];
    const float* a_dst = (const float*)d_in[8];
    const int*   ei    = (const int*)d_in[9];
    float* out = (float*)d_out;

    char* ws = (char*)d_ws;
    bf16*  hb    = (bf16*)ws;                               // 2 MB
    float* esrc  = (float*)(ws + 2097152);                  // 64 KB
    float* edst  = (float*)(ws + 2162688);                  // 64 KB
    unsigned int* bmg = (unsigned int*)(ws + 2228224);      // 2 MB adj bitmask

    void* args[] = {(void*)&x, (void*)&ev, (void*)&W, (void*)&a_src,
                    (void*)&a_dst, (void*)&ei, (void*)&hb, (void*)&esrc,
                    (void*)&edst, (void*)&bmg, (void*)&out};
    hipLaunchCooperativeKernel((const void*)fused_kernel, dim3(256), dim3(1024),
                               args, 0, stream);
}

// Round 10
// 100.506 us; speedup vs baseline: 1.7594x; 1.7594x over previous
//
#include <hip/hip_runtime.h>
#include <hip/hip_bf16.h>

// Problem constants (from reference)
#define NN    4096
#define DD    256
#define HH    4
#define DHH   64
#define EDGES 131072
#define CAP   128           // per-row neighbor capacity; deg ~ Poisson(32), P(>128) < 1e-40
#define RPB   2             // rows per attn block (1 wave per row)
#define LRELU_ALPHA 0.2f

typedef __hip_bfloat16 bf16;
typedef __attribute__((ext_vector_type(8))) short short8v;   // 8 bf16 = 4 VGPR
typedef __attribute__((ext_vector_type(4))) float f32x4;     // MFMA acc

// Round-15: REVERT to the round-6 kernel -- the empirical best (99.77 us).
// Evidence log:
//   R6 (this code)           : 99.8 us   <- best of 10 rounds
//   R7 (16-wave hproj)       : 102.8
//   R8 (LDS W-records)       : 102.9
//   R9 (cooperative fusion)  : 176.8  -- coop graph-replay overhead ~+40us,
//       1 blk/CU caps occupancy at 42%, grid.sync phase-skew, 932K LDS
//       bank conflicts in record staging. BUT its counters finally showed
//       ALL our GPU work = 77us cold-profiled, HBM 5%, MFMA 1%, VALU 12%:
//       latency-bound, not pipe-bound.
// Key insight from R9: profiled != timed. rocprof replays cold; the timed
// graph pass has x/W/ei/ev L2-WARM (input-restore writes immediately precede
// us) and hproj's outputs L2-warm for attn. Timed totals across four
// structurally different hprojs moved <=3us: our kernels are a ~15-25us slice
// of a ~100us total = 43us fill (80% HBM peak) + ~25us restore dispatches +
// launch gaps + us. This revert reproduces the best-known configuration.
//
// hproj: MFMA split-bf16 (x=xh+xl, w=wh+wl; h = xh*wh + xh*wl + xl*wh, fp32
// acc; dropped xl*wl ~1e-5, ~400x below hb's bf16 ulp). W converted inline
// from fp32 (first-touch spread over 256 blocks, overlaps x loads + MFMA).
// C/D mapping col=lane&15, row=4*(lane>>4)+reg (HW-verified); A/B k-slot
// bijection cancels. Edge mask: edge survives iff edge_vals > 0 (sigmoid(mlp)
// > 0 strictly in fp32 -> the W1/b1/W2/b2 MLP is dead w.r.t. the adj>0 mask).
//
// ws layout, 4.2 MB total:
//   hb    [N][H][DH]   bf16  @ 0         (2 MB)
//   esrc  [N][H]       f32   @ 2097152   (64 KB)
//   edst  [N][H]       f32   @ 2162688   (64 KB)
//   bmg   [N][N/32]    u32   @ 2228224   (2 MB)   <- hipMemsetAsync node

__device__ __forceinline__ float bf_lo(unsigned int u) { return __uint_as_float(u << 16); }
__device__ __forceinline__ float bf_hi(unsigned int u) { return __uint_as_float(u & 0xffff0000u); }

__device__ __forceinline__ unsigned short f2bf_rne(float f) {
    unsigned int u = __float_as_uint(f);
    return (unsigned short)((u + 0x7fffu + ((u >> 16) & 1u)) >> 16);   // RNE; no NaN here
}
__device__ __forceinline__ float bf2f(unsigned short s) {
    return __uint_as_float(((unsigned int)s) << 16);
}

// ---------------------------------------------------------------------------
// Kernel A (fused): MFMA hproj for 16 rows/block + a 512-edge slice/block.
//   grid = 256 blocks x 256 threads (4 waves). wave wv = head (cols
//   wv*64..wv*64+63 = 4 N-tiles of 16); block = M-tile of 16 rows.
//   K loop: 8 steps of 32; per (nt,ks): W fragment built inline from fp32
//   (8 loads, 64B-coalesced per 16-lane group) + 3 split MFMAs. 96 MFMA/wave.
//   Edge phase (2 edges/thread, fire-and-forget atomicOr) hides under MFMA.
//   esrc/edst from fp32 accumulators (16-lane shfl reduce over dh).
// ---------------------------------------------------------------------------
__global__ __launch_bounds__(256) void hproj_edges_kernel(
    const float* __restrict__ x, const float* __restrict__ W,
    const float* __restrict__ a_src, const float* __restrict__ a_dst,
    const int* __restrict__ ei, const float* __restrict__ ev,
    bf16* __restrict__ hb, float* __restrict__ esrc, float* __restrict__ edst,
    unsigned int* __restrict__ bmg)
{
    const int t = threadIdx.x;
    const int i0 = blockIdx.x * 16;

    // edge slice: 512 edges/block, 2 per thread, fire-and-forget OR
    {
        const int   e0 = blockIdx.x * 512 + t;
        const int   e1 = e0 + 256;
        const float v0 = ev[e0], v1 = ev[e1];
        const int   r0 = ei[e0], c0 = ei[EDGES + e0];
        const int   r1 = ei[e1], c1 = ei[EDGES + e1];
        if (v0 > 0.f) atomicOr(&bmg[r0 * (NN / 32) + (c0 >> 5)], 1u << (c0 & 31));
        if (v1 > 0.f) atomicOr(&bmg[r1 * (NN / 32) + (c1 >> 5)], 1u << (c1 & 31));
    }

    const int wv   = t >> 6;        // wave = head
    const int lane = t & 63;
    const int mrow = lane & 15;     // A row / C col index
    const int kgrp = lane >> 4;     // k-group / C row group

    const float* xp = x + (size_t)(i0 + mrow) * DD + 8 * kgrp;
    // W base for this wave's head + this lane's (kgrp, mrow):
    //   element (q,ks,e) at  Wb[(ks*32 + 8*kgrp + e)*DHH + q*16]
    const float* Wb = W + (size_t)wv * (DD * DHH) + mrow;

    f32x4 acc[4];
    #pragma unroll
    for (int q = 0; q < 4; ++q) acc[q] = (f32x4){0.f, 0.f, 0.f, 0.f};

    #pragma unroll
    for (int ks = 0; ks < 8; ++ks) {
        // A fragment: x split hi/lo on the fly
        const float4 u0 = *(const float4*)(xp + ks * 32);
        const float4 u1 = *(const float4*)(xp + ks * 32 + 4);
        const float v[8] = {u0.x, u0.y, u0.z, u0.w, u1.x, u1.y, u1.z, u1.w};
        short8v ah, al;
        #pragma unroll
        for (int e = 0; e < 8; ++e) {
            const unsigned short hi = f2bf_rne(v[e]);
            ah[e] = (short)hi;
            al[e] = (short)f2bf_rne(v[e] - bf2f(hi));
        }
        const float* wk = Wb + (size_t)(ks * 32 + 8 * kgrp) * DHH;
        #pragma unroll
        for (int q = 0; q < 4; ++q) {
            // B fragment inline from fp32 W
            short8v bh, bl;
            #pragma unroll
            for (int e = 0; e < 8; ++e) {
                const float wv_e = wk[(size_t)e * DHH + q * 16];
                const unsigned short hi = f2bf_rne(wv_e);
                bh[e] = (short)hi;
                bl[e] = (short)f2bf_rne(wv_e - bf2f(hi));
            }
            acc[q] = __builtin_amdgcn_mfma_f32_16x16x32_bf16(ah, bh, acc[q], 0, 0, 0);
            acc[q] = __builtin_amdgcn_mfma_f32_16x16x32_bf16(ah, bl, acc[q], 0, 0, 0);
            acc[q] = __builtin_amdgcn_mfma_f32_16x16x32_bf16(al, bh, acc[q], 0, 0, 0);
        }
    }

    // hb store: C/D mapping col=mrow (within tile q), row=4*kgrp+reg
    #pragma unroll
    for (int q = 0; q < 4; ++q) {
        const int col = wv * 64 + q * 16 + mrow;
        #pragma unroll
        for (int reg = 0; reg < 4; ++reg) {
            const int row = i0 + 4 * kgrp + reg;
            hb[(size_t)row * (HH * DHH) + col] = __float2bfloat16(acc[q][reg]);
        }
    }

    // esrc/edst: dot over dh for this head; reduce over mrow (16-lane groups)
    float vs[4] = {0.f, 0.f, 0.f, 0.f}, vd[4] = {0.f, 0.f, 0.f, 0.f};
    #pragma unroll
    for (int q = 0; q < 4; ++q) {
        const float as = a_src[wv * DHH + q * 16 + mrow];
        const float ad = a_dst[wv * DHH + q * 16 + mrow];
        #pragma unroll
        for (int reg = 0; reg < 4; ++reg) {
            vs[reg] = fmaf(acc[q][reg], as, vs[reg]);
            vd[reg] = fmaf(acc[q][reg], ad, vd[reg]);
        }
    }
    #pragma unroll
    for (int reg = 0; reg < 4; ++reg) {
        #pragma unroll
        for (int off = 1; off < 16; off <<= 1) {
            vs[reg] += __shfl_xor(vs[reg], off, 64);
            vd[reg] += __shfl_xor(vd[reg], off, 64);
        }
    }
    if (mrow == 0) {
        #pragma unroll
        for (int reg = 0; reg < 4; ++reg) {
            const int row = i0 + 4 * kgrp + reg;
            esrc[row * HH + wv] = vs[reg];
            edst[row * HH + wv] = vd[reg];
        }
    }
}

// ---------------------------------------------------------------------------
// Kernel B: 2 rows/block, 1 wave/row, 128 threads, grid = NN/2 = 2048.
// ---------------------------------------------------------------------------
__global__ __launch_bounds__(128) void attn_kernel(
    const unsigned int* __restrict__ bmg, const bf16* __restrict__ hb,
    const float* __restrict__ esrc, const float* __restrict__ edst,
    float* __restrict__ out)
{
    __shared__ int nbr[RPB][CAP];
    __shared__ __align__(16) float wts[RPB][CAP][HH];   // [row][k][head]

    const int t = threadIdx.x;
    const int r = t >> 6, lane = t & 63;
    const int i = blockIdx.x * RPB + r;

    // ---- bitmask -> compact neighbor list (wave-parallel, no atomics) ----
    const uint2 wp = *(const uint2*)(bmg + (size_t)i * (NN / 32) + 2 * lane);
    const int c = __popc(wp.x) + __popc(wp.y);
    int inc = c;
    #pragma unroll
    for (int off = 1; off < 64; off <<= 1) {
        const int nn = __shfl_up(inc, off, 64);
        if (lane >= off) inc += nn;
    }
    int p = inc - c;
    const int deg = min(__shfl(inc, 63, 64), CAP);
    unsigned int w = wp.x;
    while (w) { const int b = __ffs(w) - 1; w &= w - 1; if (p < CAP) nbr[r][p] = (lane << 6) + b; ++p; }
    w = wp.y;
    while (w) { const int b = __ffs(w) - 1; w &= w - 1; if (p < CAP) nbr[r][p] = (lane << 6) + 32 + b; ++p; }
    __syncthreads();

    const int head = lane >> 4;          // lane covers dims [4*lane, 4*lane+3]
    float4 acc = make_float4(0.f, 0.f, 0.f, 0.f);
    float4 sm  = make_float4(0.f, 0.f, 0.f, 0.f);

    if (deg > 0) {
        const float4 es4 = *(const float4*)(esrc + (size_t)i * HH);
        float4 mx = make_float4(-INFINITY, -INFINITY, -INFINITY, -INFINITY);
        // pass 1: logits (all 4 heads per lane), track max
        for (int k = lane; k < deg; k += 64) {
            const float4 ed = *(const float4*)(edst + (size_t)nbr[r][k] * HH);
            float4 e4;
            e4.x = es4.x + ed.x; e4.x = e4.x > 0.f ? e4.x : LRELU_ALPHA * e4.x;
            e4.y = es4.y + ed.y; e4.y = e4.y > 0.f ? e4.y : LRELU_ALPHA * e4.y;
            e4.z = es4.z + ed.z; e4.z = e4.z > 0.f ? e4.z : LRELU_ALPHA * e4.z;
            e4.w = es4.w + ed.w; e4.w = e4.w > 0.f ? e4.w : LRELU_ALPHA * e4.w;
            *(float4*)&wts[r][k][0] = e4;
            mx.x = fmaxf(mx.x, e4.x); mx.y = fmaxf(mx.y, e4.y);
            mx.z = fmaxf(mx.z, e4.z); mx.w = fmaxf(mx.w, e4.w);
        }
        #pragma unroll
        for (int off = 32; off; off >>= 1) {
            mx.x = fmaxf(mx.x, __shfl_xor(mx.x, off, 64));
            mx.y = fmaxf(mx.y, __shfl_xor(mx.y, off, 64));
            mx.z = fmaxf(mx.z, __shfl_xor(mx.z, off, 64));
            mx.w = fmaxf(mx.w, __shfl_xor(mx.w, off, 64));
        }
        // pass 2: exponentiate in place, track sum
        for (int k = lane; k < deg; k += 64) {
            float4 e4 = *(const float4*)&wts[r][k][0];
            e4.x = expf(e4.x - mx.x); e4.y = expf(e4.y - mx.y);
            e4.z = expf(e4.z - mx.z); e4.w = expf(e4.w - mx.w);
            *(float4*)&wts[r][k][0] = e4;
            sm.x += e4.x; sm.y += e4.y; sm.z += e4.z; sm.w += e4.w;
        }
        #pragma unroll
        for (int off = 32; off; off >>= 1) {
            sm.x += __shfl_xor(sm.x, off, 64);
            sm.y += __shfl_xor(sm.y, off, 64);
            sm.z += __shfl_xor(sm.z, off, 64);
            sm.w += __shfl_xor(sm.w, off, 64);
        }
    }
    __syncthreads();   // wts visible across lanes (uniform barrier count per block)

    float inv;
    if (deg == 0) {
        // uniform attention over all N columns: out = mean of h
        const uint2* hp = (const uint2*)hb + lane;   // row j = 64 uint2's
        for (int j = 0; j < NN; ++j) {
            const uint2 u = hp[(size_t)j * 64];
            acc.x += bf_lo(u.x); acc.y += bf_hi(u.x);
            acc.z += bf_lo(u.y); acc.w += bf_hi(u.y);
        }
        inv = 1.f / NN;
    } else {
        // pass 3: acc_d = sum_k w[head][k] * h[j_k][d]; 4 gathers in flight
        const uint2* hp = (const uint2*)hb;
        int k = 0;
        for (; k + 3 < deg; k += 4) {
            const int j0 = nbr[r][k],     j1 = nbr[r][k + 1];
            const int j2 = nbr[r][k + 2], j3 = nbr[r][k + 3];
            const uint2 u0 = hp[(size_t)j0 * 64 + lane];
            const uint2 u1 = hp[(size_t)j1 * 64 + lane];
            const uint2 u2 = hp[(size_t)j2 * 64 + lane];
            const uint2 u3 = hp[(size_t)j3 * 64 + lane];
            const float w0 = wts[r][k][head],     w1 = wts[r][k + 1][head];
            const float w2 = wts[r][k + 2][head], w3 = wts[r][k + 3][head];
            acc.x = fmaf(w0, bf_lo(u0.x), acc.x); acc.y = fmaf(w0, bf_hi(u0.x), acc.y);
            acc.z = fmaf(w0, bf_lo(u0.y), acc.z); acc.w = fmaf(w0, bf_hi(u0.y), acc.w);
            acc.x = fmaf(w1, bf_lo(u1.x), acc.x); acc.y = fmaf(w1, bf_hi(u1.x), acc.y);
            acc.z = fmaf(w1, bf_lo(u1.y), acc.z); acc.w = fmaf(w1, bf_hi(u1.y), acc.w);
            acc.x = fmaf(w2, bf_lo(u2.x), acc.x); acc.y = fmaf(w2, bf_hi(u2.x), acc.y);
            acc.z = fmaf(w2, bf_lo(u2.y), acc.z); acc.w = fmaf(w2, bf_hi(u2.y), acc.w);
            acc.x = fmaf(w3, bf_lo(u3.x), acc.x); acc.y = fmaf(w3, bf_hi(u3.x), acc.y);
            acc.z = fmaf(w3, bf_lo(u3.y), acc.z); acc.w = fmaf(w3, bf_hi(u3.y), acc.w);
        }
        for (; k < deg; ++k) {
            const uint2 u = hp[(size_t)nbr[r][k] * 64 + lane];
            const float wk = wts[r][k][head];
            acc.x = fmaf(wk, bf_lo(u.x), acc.x); acc.y = fmaf(wk, bf_hi(u.x), acc.y);
            acc.z = fmaf(wk, bf_lo(u.y), acc.z); acc.w = fmaf(wk, bf_hi(u.y), acc.w);
        }
        const float s = head == 0 ? sm.x : head == 1 ? sm.y : head == 2 ? sm.z : sm.w;
        inv = 1.f / s;
    }

    float4 o;
    o.x = acc.x * inv; o.y = acc.y * inv; o.z = acc.z * inv; o.w = acc.w * inv;
    *(float4*)(out + (size_t)i * (HH * DHH) + 4 * lane) = o;   // fp32 output
}

// ---------------------------------------------------------------------------
extern "C" void kernel_launch(void* const* d_in, const int* in_sizes, int n_in,
                              void* d_out, int out_size, void* d_ws, size_t ws_size,
                              hipStream_t stream)
{
    const float* x     = (const float*)d_in[0];
    const float* ev    = (const float*)d_in[1];
    // d_in[2..5] = W1,b1,W2,b2 (edge MLP) -- provably irrelevant to the output
    const float* W     = (const float*)d_in[6];
    const float* a_src = (const float*)d_in[7];
    const float* a_dst = (const float*)d_in[8];
    const int*   ei    = (const int*)d_in[9];
    float* out = (float*)d_out;

    char* ws = (char*)d_ws;
    bf16*  hb    = (bf16*)ws;                               // 2 MB
    float* esrc  = (float*)(ws + 2097152);                  // 64 KB
    float* edst  = (float*)(ws + 2162688);                  // 64 KB
    unsigned int* bmg = (unsigned int*)(ws + 2228224);      // 2 MB adj bitmask

    hipMemsetAsync(bmg, 0, NN * (NN / 32) * sizeof(unsigned int), stream);
    hproj_edges_kernel<<<NN / 16, 256, 0, stream>>>(x, W, a_src, a_dst, ei, ev,
                                                    hb, esrc, edst, bmg);
    attn_kernel<<<NN / RPB, 128, 0, stream>>>(bmg, hb, esrc, edst, out);
}